// Round 10
// baseline (3330.428 us; speedup 1.0000x reference)
//
#include <hip/hip_runtime.h>

// Problem constants: B=32, S=1024, I=1024, H=1024, W is (H, I+H)
#define B_ 32
#define S_ 1024
#define H_ 1024
#define NWG 64            // 2 batch-groups x 32 col-groups
#define EXN (32 * 1024)   // u16 cells per parity buffer (32 batches x 1024 cols)

typedef float f32x4 __attribute__((ext_vector_type(4)));
typedef short bf16x8 __attribute__((ext_vector_type(8)));
typedef unsigned int u32x4 __attribute__((ext_vector_type(4)));
typedef unsigned short u16;

__device__ __forceinline__ short f2bf(float f) {
  union { float f; unsigned u; } v; v.f = f;
  unsigned r = v.u + 0x7FFFu + ((v.u >> 16) & 1u);
  return (short)(r >> 16);
}

// ============================================================================
// Kernel 1: xz GEMM (R1-verified, unchanged).
//   C[m][n] = sum_k x[m][k] * W[n][1024+k] + bias[n] -> d_out in-place.
// ============================================================================
__global__ __launch_bounds__(256) void xz_gemm(
    const float* __restrict__ X, const float* __restrict__ W,
    const float* __restrict__ bias, float* __restrict__ C) {
  __shared__ short As[128][40];
  __shared__ short Bs[128][40];
  const int tid  = threadIdx.x;
  const int lane = tid & 63, wave = tid >> 6;
  const int m0 = blockIdx.y * 128, n0 = blockIdx.x * 128;
  const int wm = (wave >> 1) * 64, wn = (wave & 1) * 64;
  const int jl = lane & 15, kq = lane >> 4;
  const int sr = tid >> 2, skg = (tid & 3) * 8;

  f32x4 zero4 = {0.f, 0.f, 0.f, 0.f};
  f32x4 acc[4][4];
  #pragma unroll
  for (int mi = 0; mi < 4; ++mi)
    #pragma unroll
    for (int ni = 0; ni < 4; ++ni) acc[mi][ni] = zero4;

  for (int k0 = 0; k0 < 1024; k0 += 32) {
    #pragma unroll
    for (int rr = 0; rr < 2; ++rr) {
      int row = sr + rr * 64;
      const float* pa = X + (size_t)(m0 + row) * 1024 + k0 + skg;
      f32x4 a0 = *(const f32x4*)pa;
      f32x4 a1 = *(const f32x4*)(pa + 4);
      bf16x8 pk;
      #pragma unroll
      for (int e = 0; e < 4; ++e) { pk[e] = f2bf(a0[e]); pk[e + 4] = f2bf(a1[e]); }
      *(bf16x8*)&As[row][skg] = pk;
      const float* pb = W + (size_t)(n0 + row) * 2048 + 1024 + k0 + skg;
      f32x4 b0 = *(const f32x4*)pb;
      f32x4 b1 = *(const f32x4*)(pb + 4);
      bf16x8 qk;
      #pragma unroll
      for (int e = 0; e < 4; ++e) { qk[e] = f2bf(b0[e]); qk[e + 4] = f2bf(b1[e]); }
      *(bf16x8*)&Bs[row][skg] = qk;
    }
    __syncthreads();
    bf16x8 af[4], bfv[4];
    #pragma unroll
    for (int mi = 0; mi < 4; ++mi) af[mi] = *(const bf16x8*)&As[wm + mi * 16 + jl][kq * 8];
    #pragma unroll
    for (int ni = 0; ni < 4; ++ni) bfv[ni] = *(const bf16x8*)&Bs[wn + ni * 16 + jl][kq * 8];
    #pragma unroll
    for (int mi = 0; mi < 4; ++mi)
      #pragma unroll
      for (int ni = 0; ni < 4; ++ni)
        acc[mi][ni] = __builtin_amdgcn_mfma_f32_16x16x32_bf16(af[mi], bfv[ni], acc[mi][ni], 0, 0, 0);
    __syncthreads();
  }
  #pragma unroll
  for (int ni = 0; ni < 4; ++ni) {
    int col = n0 + wn + ni * 16 + jl;
    float bv = bias[col];
    #pragma unroll
    for (int mi = 0; mi < 4; ++mi) {
      int rbase = m0 + wm + mi * 16 + kq * 4;
      #pragma unroll
      for (int r = 0; r < 4; ++r)
        C[(size_t)(rbase + r) * 1024 + col] = acc[mi][ni][r] + bv;
    }
  }
}

// ============================================================================
// Kernel 2: recurrence, tagged-granule exchange, PURE fire-and-forget.
//   64 wgs = 2bg x 32cg, 512 thr (8 waves, K-split 128/wave).
//   Exchange cell = bf16(h); col==7 (mod 8) carries tag ((v>>1)&1) in its
//   mantissa LSB; version v lives in parity buffer v&1. Producers butterfly
//   8 cells into one lane -> ONE 16B store (atomic granule). NO acks, NO
//   flags: consumers spin on the data loads themselves; visibility of a
//   version-v granule from producer Z proves Z finished reading v-1
//   (transitive barrier argument, R3/R9) -> WAR-safe; tag at distance 2
//   differs, distance-4 ABA excluded by the same chain. Spin is bounded
//   (diagnostic escape) so a protocol bug fails fast instead of hanging.
// ============================================================================
__global__ __launch_bounds__(512) void lstm_rec(
    const float* __restrict__ W, const float* __restrict__ h0,
    const float* __restrict__ c0, float* __restrict__ out,
    u16* __restrict__ exch) {
  __shared__ float zred[2][8][2][64][5];    // 40 KB, parity-dbuf, pad 5
  const int tid  = threadIdx.x;
  const int lane = tid & 63, wave = tid >> 6;
  const int jl = lane & 15, kq = lane >> 4;
  const int bg = blockIdx.x >> 5;
  const int cg = blockIdx.x & 31;

  // --- owner thread (bp, cp) owns cell (b, col)
  const int bp  = tid >> 5;
  const int cp  = tid & 31;
  const int b   = bg * 16 + bp;
  const int col = cg * 32 + cp;
  float cst  = c0[b * 1024 + col];
  float hcur = h0[b * 1024 + col];

  // PUBLISH(h, ver): butterfly 8 lanes' u16 cells into one 16B granule,
  // tag in cell (col%8==7)'s LSB, single dwordx4 store to parity (ver&1).
#define PUBLISH(HVAL, VER) do {                                               \
    unsigned hb = (unsigned)(u16)f2bf(HVAL);                                  \
    if ((cp & 7) == 7) hb = (hb & 0xFFFEu) | (((unsigned)(VER) >> 1) & 1u);   \
    unsigned ot = (unsigned)__shfl_xor((int)hb, 1);                           \
    unsigned v0 = (lane & 1) ? (ot | (hb << 16)) : (hb | (ot << 16));         \
    unsigned o2 = (unsigned)__shfl_xor((int)v0, 2);                           \
    unsigned w0 = (lane & 2) ? o2 : v0;                                       \
    unsigned w1 = (lane & 2) ? v0 : o2;                                       \
    unsigned o0 = (unsigned)__shfl_xor((int)w0, 4);                           \
    unsigned o1 = (unsigned)__shfl_xor((int)w1, 4);                           \
    u32x4 g;                                                                  \
    g[0] = (lane & 4) ? o0 : w0;  g[1] = (lane & 4) ? o1 : w1;                \
    g[2] = (lane & 4) ? w0 : o0;  g[3] = (lane & 4) ? w1 : o1;                \
    if ((lane & 7) == 0) {                                                    \
      u16* dp = exch + (size_t)((VER) & 1) * EXN + b * 1024 + (col & ~7);     \
      asm volatile("global_store_dwordx4 %0, %1, off sc0 sc1"                 \
                   :: "v"(dp), "v"(g) : "memory");                            \
    }                                                                         \
  } while (0)

  PUBLISH(hcur, 0);                         // version 0 = h0, fire-and-forget

  // --- Wh fragments direct global -> registers (constant over t)
  bf16x8 bfr[2][4];
  #pragma unroll
  for (int ct = 0; ct < 2; ++ct)
    #pragma unroll
    for (int kk = 0; kk < 4; ++kk) {
      const float* pw = W + (size_t)(cg * 32 + ct * 16 + jl) * 2048
                          + wave * 128 + kk * 32 + kq * 8;   // Wh = W[:, :1024]
      f32x4 a0 = *(const f32x4*)pw;
      f32x4 a1 = *(const f32x4*)(pw + 4);
      bf16x8 pk;
      #pragma unroll
      for (int e = 0; e < 4; ++e) { pk[e] = f2bf(a0[e]); pk[e + 4] = f2bf(a1[e]); }
      bfr[ct][kk] = pk;
    }

  const int ct_o = cp >> 4;
  const int lred = ((bp >> 2) << 4) | (cp & 15);
  const int rred = bp & 3;
  const size_t obase = (size_t)b * (S_ * H_) + col;
  const u16* aB = exch + (size_t)(bg * 16 + jl) * 1024 + wave * 128 + kq * 8;

  float xz = out[obase];                    // xz for t=0

  for (int t = 0; t < S_; ++t) {
    const int p = t & 1;
    const unsigned etg = (unsigned)((t >> 1) & 1);
    const u16* src = aB + (size_t)p * EXN;

    // ---- spin on self-validating granule loads (detection IS the transfer)
    u32x4 L0, L1, L2, L3;
    int spin = 0;
    for (;;) {
      asm volatile("global_load_dwordx4 %0, %1, off sc0 sc1"
                   : "=v"(L0) : "v"(src) : "memory");
      asm volatile("global_load_dwordx4 %0, %1, off offset:64 sc0 sc1"
                   : "=v"(L1) : "v"(src) : "memory");
      asm volatile("global_load_dwordx4 %0, %1, off offset:128 sc0 sc1"
                   : "=v"(L2) : "v"(src) : "memory");
      asm volatile("global_load_dwordx4 %0, %1, off offset:192 sc0 sc1"
                   : "=v"(L3) : "v"(src) : "memory");
      asm volatile("s_waitcnt vmcnt(0)" ::: "memory");
      __builtin_amdgcn_sched_barrier(0);
      unsigned bad = ((L0[3] >> 16) ^ etg) | ((L1[3] >> 16) ^ etg)
                   | ((L2[3] >> 16) ^ etg) | ((L3[3] >> 16) ^ etg);
      if (__all((bad & 1u) == 0u)) break;
      if (++spin >= 16384) break;           // diagnostic escape, never in practice
      if (spin > 48) __builtin_amdgcn_s_sleep(2);
    }

    // ---- MFMA partials into parity zred (granules ARE the A-fragments)
    union { u32x4 u; bf16x8 h; } q0, q1, q2, q3;
    q0.u = L0; q1.u = L1; q2.u = L2; q3.u = L3;
    bf16x8 afr[4] = {q0.h, q1.h, q2.h, q3.h};
    #pragma unroll
    for (int ct = 0; ct < 2; ++ct) {
      f32x4 pacc = {0.f, 0.f, 0.f, 0.f};
      #pragma unroll
      for (int kk = 0; kk < 4; ++kk)
        pacc = __builtin_amdgcn_mfma_f32_16x16x32_bf16(afr[kk], bfr[ct][kk], pacc, 0, 0, 0);
      #pragma unroll
      for (int r = 0; r < 4; ++r)
        zred[p][wave][ct][lane][r] = pacc[r];
    }

    __syncthreads();   // the ONLY barrier per step

    // ---- owner: reduce 8 waves, gates (rcpf), publish v = t+1 (fire & forget)
    float z = xz;
    #pragma unroll
    for (int w = 0; w < 8; ++w) z += zred[p][w][ct_o][lred][rred];
    float u  = __expf(-z);
    float u2 = u * u;
    float sg = __builtin_amdgcn_rcpf(1.f + u);                 // sigmoid(z)
    float tz = (1.f - u2) * __builtin_amdgcn_rcpf(1.f + u2);   // tanh(z)
    cst  = sg * (cst + tz);
    float v  = __expf(-2.f * cst);
    float tc = (1.f - v) * __builtin_amdgcn_rcpf(1.f + v);     // tanh(c)
    hcur = sg * tc;

    PUBLISH(hcur, t + 1);                   // no ack, no flag — straight to spin

    // off the critical path: fp32 output + next xz prefetch (latency hides
    // under the next step's spin; value consumed a full step later)
    out[obase + (size_t)t * H_] = hcur;
    xz = out[obase + (size_t)(t + 1 < S_ ? t + 1 : t) * H_];
  }
#undef PUBLISH

  // ---- hn, cn
  const size_t OFS = (size_t)B_ * S_ * H_;
  out[OFS + b * 1024 + col] = hcur;
  out[OFS + (size_t)B_ * H_ + b * 1024 + col] = cst;
}

// ============================================================================
extern "C" void kernel_launch(void* const* d_in, const int* in_sizes, int n_in,
                              void* d_out, int out_size, void* d_ws, size_t ws_size,
                              hipStream_t stream) {
  const float* x    = (const float*)d_in[0];
  const float* h0   = (const float*)d_in[1];
  const float* c0   = (const float*)d_in[2];
  const float* W    = (const float*)d_in[3];
  const float* bias = (const float*)d_in[4];
  float* out = (float*)d_out;

  u16* exch = (u16*)d_ws;   // 2 x 64 KB ping-pong, bf16 cells w/ LSB tags
  // 0xFF => every stale tag bit reads 1, mismatching the first expected tag
  // (0) in both parities; also kills cross-replay staleness.
  hipMemsetAsync(exch, 0xFF, 2 * EXN * sizeof(u16), stream);

  xz_gemm<<<dim3(8, 256), 256, 0, stream>>>(x, W, bias, out);
  lstm_rec<<<dim3(NWG), 512, 0, stream>>>(W, h0, c0, out, exch);
}

// Round 11
// 2350.656 us; speedup vs baseline: 1.4168x; 1.4168x over previous
//
#include <hip/hip_runtime.h>

// Problem constants: B=32, S=1024, I=1024, H=1024, W is (H, I+H)
#define B_ 32
#define S_ 1024
#define H_ 1024
#define NWG 64            // 2 batch-groups x 32 col-groups
#define EXN (32 * 1024)   // u16 cells per parity buffer (32 batches x 1024 cols)

typedef float f32x4 __attribute__((ext_vector_type(4)));
typedef short bf16x8 __attribute__((ext_vector_type(8)));
typedef unsigned int u32x4 __attribute__((ext_vector_type(4)));
typedef unsigned short u16;

__device__ __forceinline__ short f2bf(float f) {
  union { float f; unsigned u; } v; v.f = f;
  unsigned r = v.u + 0x7FFFu + ((v.u >> 16) & 1u);
  return (short)(r >> 16);
}

// ============================================================================
// Kernel 1: xz GEMM (R1-verified, unchanged).
//   C[m][n] = sum_k x[m][k] * W[n][1024+k] + bias[n] -> d_out in-place.
// ============================================================================
__global__ __launch_bounds__(256) void xz_gemm(
    const float* __restrict__ X, const float* __restrict__ W,
    const float* __restrict__ bias, float* __restrict__ C) {
  __shared__ short As[128][40];
  __shared__ short Bs[128][40];
  const int tid  = threadIdx.x;
  const int lane = tid & 63, wave = tid >> 6;
  const int m0 = blockIdx.y * 128, n0 = blockIdx.x * 128;
  const int wm = (wave >> 1) * 64, wn = (wave & 1) * 64;
  const int jl = lane & 15, kq = lane >> 4;
  const int sr = tid >> 2, skg = (tid & 3) * 8;

  f32x4 zero4 = {0.f, 0.f, 0.f, 0.f};
  f32x4 acc[4][4];
  #pragma unroll
  for (int mi = 0; mi < 4; ++mi)
    #pragma unroll
    for (int ni = 0; ni < 4; ++ni) acc[mi][ni] = zero4;

  for (int k0 = 0; k0 < 1024; k0 += 32) {
    #pragma unroll
    for (int rr = 0; rr < 2; ++rr) {
      int row = sr + rr * 64;
      const float* pa = X + (size_t)(m0 + row) * 1024 + k0 + skg;
      f32x4 a0 = *(const f32x4*)pa;
      f32x4 a1 = *(const f32x4*)(pa + 4);
      bf16x8 pk;
      #pragma unroll
      for (int e = 0; e < 4; ++e) { pk[e] = f2bf(a0[e]); pk[e + 4] = f2bf(a1[e]); }
      *(bf16x8*)&As[row][skg] = pk;
      const float* pb = W + (size_t)(n0 + row) * 2048 + 1024 + k0 + skg;
      f32x4 b0 = *(const f32x4*)pb;
      f32x4 b1 = *(const f32x4*)(pb + 4);
      bf16x8 qk;
      #pragma unroll
      for (int e = 0; e < 4; ++e) { qk[e] = f2bf(b0[e]); qk[e + 4] = f2bf(b1[e]); }
      *(bf16x8*)&Bs[row][skg] = qk;
    }
    __syncthreads();
    bf16x8 af[4], bfv[4];
    #pragma unroll
    for (int mi = 0; mi < 4; ++mi) af[mi] = *(const bf16x8*)&As[wm + mi * 16 + jl][kq * 8];
    #pragma unroll
    for (int ni = 0; ni < 4; ++ni) bfv[ni] = *(const bf16x8*)&Bs[wn + ni * 16 + jl][kq * 8];
    #pragma unroll
    for (int mi = 0; mi < 4; ++mi)
      #pragma unroll
      for (int ni = 0; ni < 4; ++ni)
        acc[mi][ni] = __builtin_amdgcn_mfma_f32_16x16x32_bf16(af[mi], bfv[ni], acc[mi][ni], 0, 0, 0);
    __syncthreads();
  }
  #pragma unroll
  for (int ni = 0; ni < 4; ++ni) {
    int col = n0 + wn + ni * 16 + jl;
    float bv = bias[col];
    #pragma unroll
    for (int mi = 0; mi < 4; ++mi) {
      int rbase = m0 + wm + mi * 16 + kq * 4;
      #pragma unroll
      for (int r = 0; r < 4; ++r)
        C[(size_t)(rbase + r) * 1024 + col] = acc[mi][ni][r] + bv;
    }
  }
}

// ============================================================================
// Kernel 2: recurrence, tagged-granule exchange, fire-and-forget + PACED.
//   64 wgs = 2bg x 32cg, 512 thr (8 waves, K-split 128/wave).
//   Exchange cell = bf16(h); col==7 (mod 8) carries tag ((v>>1)&1) in its
//   mantissa LSB; version v lives in parity buffer v&1. Producers butterfly
//   8 cells into one lane -> ONE 16B store (atomic granule). No flags.
//   R10 lesson: a post-publish vmcnt(0) drain is REQUIRED pacing — it
//   overlaps our store-ack with peers' publish window so the next spin's
//   first attempt usually succeeds; without it every step eats 1-2 extra
//   full retry round trips. Order: publish -> out-store -> drain -> xz
//   prefetch (overlaps next spin) -> spin.
//   WAR/ABA safety: transitive barrier argument (R3/R9/R10) — visibility of
//   producer Z's version-v granule proves Z consumed v-1; tags differ at
//   distance 2; distance-4 ABA excluded by the chain. Spin bounded
//   (diagnostic escape) so a protocol bug fails fast, never hangs.
// ============================================================================
__global__ __launch_bounds__(512) void lstm_rec(
    const float* __restrict__ W, const float* __restrict__ h0,
    const float* __restrict__ c0, float* __restrict__ out,
    u16* __restrict__ exch) {
  __shared__ float zred[2][8][2][64][5];    // 40 KB, parity-dbuf, pad 5
  const int tid  = threadIdx.x;
  const int lane = tid & 63, wave = tid >> 6;
  const int jl = lane & 15, kq = lane >> 4;
  const int bg = blockIdx.x >> 5;
  const int cg = blockIdx.x & 31;

  // --- owner thread (bp, cp) owns cell (b, col)
  const int bp  = tid >> 5;
  const int cp  = tid & 31;
  const int b   = bg * 16 + bp;
  const int col = cg * 32 + cp;
  float cst  = c0[b * 1024 + col];
  float hcur = h0[b * 1024 + col];

  // PUBLISH(h, ver): butterfly 8 lanes' u16 cells into one 16B granule,
  // tag in cell (col%8==7)'s LSB, single dwordx4 store to parity (ver&1).
#define PUBLISH(HVAL, VER) do {                                               \
    unsigned hb = (unsigned)(u16)f2bf(HVAL);                                  \
    if ((cp & 7) == 7) hb = (hb & 0xFFFEu) | (((unsigned)(VER) >> 1) & 1u);   \
    unsigned ot = (unsigned)__shfl_xor((int)hb, 1);                           \
    unsigned v0 = (lane & 1) ? (ot | (hb << 16)) : (hb | (ot << 16));         \
    unsigned o2 = (unsigned)__shfl_xor((int)v0, 2);                           \
    unsigned w0 = (lane & 2) ? o2 : v0;                                       \
    unsigned w1 = (lane & 2) ? v0 : o2;                                       \
    unsigned o0 = (unsigned)__shfl_xor((int)w0, 4);                           \
    unsigned o1 = (unsigned)__shfl_xor((int)w1, 4);                           \
    u32x4 g;                                                                  \
    g[0] = (lane & 4) ? o0 : w0;  g[1] = (lane & 4) ? o1 : w1;                \
    g[2] = (lane & 4) ? w0 : o0;  g[3] = (lane & 4) ? w1 : o1;                \
    if ((lane & 7) == 0) {                                                    \
      u16* dp = exch + (size_t)((VER) & 1) * EXN + b * 1024 + (col & ~7);     \
      asm volatile("global_store_dwordx4 %0, %1, off sc0 sc1"                 \
                   :: "v"(dp), "v"(g) : "memory");                            \
    }                                                                         \
  } while (0)

  PUBLISH(hcur, 0);                         // version 0 = h0

  // --- Wh fragments direct global -> registers (constant over t)
  bf16x8 bfr[2][4];
  #pragma unroll
  for (int ct = 0; ct < 2; ++ct)
    #pragma unroll
    for (int kk = 0; kk < 4; ++kk) {
      const float* pw = W + (size_t)(cg * 32 + ct * 16 + jl) * 2048
                          + wave * 128 + kk * 32 + kq * 8;   // Wh = W[:, :1024]
      f32x4 a0 = *(const f32x4*)pw;
      f32x4 a1 = *(const f32x4*)(pw + 4);
      bf16x8 pk;
      #pragma unroll
      for (int e = 0; e < 4; ++e) { pk[e] = f2bf(a0[e]); pk[e + 4] = f2bf(a1[e]); }
      bfr[ct][kk] = pk;
    }

  const int ct_o = cp >> 4;
  const int lred = ((bp >> 2) << 4) | (cp & 15);
  const int rred = bp & 3;
  const size_t obase = (size_t)b * (S_ * H_) + col;
  const u16* aB = exch + (size_t)(bg * 16 + jl) * 1024 + wave * 128 + kq * 8;

  asm volatile("s_waitcnt vmcnt(0)" ::: "memory");   // pace prologue publish
  float xz = out[obase];                    // xz for t=0

  for (int t = 0; t < S_; ++t) {
    const int p = t & 1;
    const unsigned etg = (unsigned)((t >> 1) & 1);
    const u16* src = aB + (size_t)p * EXN;

    // ---- spin on self-validating granule loads (detection IS the transfer)
    u32x4 L0, L1, L2, L3;
    int spin = 0;
    for (;;) {
      asm volatile("global_load_dwordx4 %0, %1, off sc0 sc1"
                   : "=v"(L0) : "v"(src) : "memory");
      asm volatile("global_load_dwordx4 %0, %1, off offset:64 sc0 sc1"
                   : "=v"(L1) : "v"(src) : "memory");
      asm volatile("global_load_dwordx4 %0, %1, off offset:128 sc0 sc1"
                   : "=v"(L2) : "v"(src) : "memory");
      asm volatile("global_load_dwordx4 %0, %1, off offset:192 sc0 sc1"
                   : "=v"(L3) : "v"(src) : "memory");
      asm volatile("s_waitcnt vmcnt(0)" ::: "memory");
      __builtin_amdgcn_sched_barrier(0);
      unsigned bad = ((L0[3] >> 16) ^ etg) | ((L1[3] >> 16) ^ etg)
                   | ((L2[3] >> 16) ^ etg) | ((L3[3] >> 16) ^ etg);
      if (__all((bad & 1u) == 0u)) break;
      if (++spin >= 16384) break;           // diagnostic escape, never in practice
      if (spin > 256) __builtin_amdgcn_s_sleep(2);
    }

    // ---- MFMA partials into parity zred (granules ARE the A-fragments)
    union { u32x4 u; bf16x8 h; } q0, q1, q2, q3;
    q0.u = L0; q1.u = L1; q2.u = L2; q3.u = L3;
    bf16x8 afr[4] = {q0.h, q1.h, q2.h, q3.h};
    #pragma unroll
    for (int ct = 0; ct < 2; ++ct) {
      f32x4 pacc = {0.f, 0.f, 0.f, 0.f};
      #pragma unroll
      for (int kk = 0; kk < 4; ++kk)
        pacc = __builtin_amdgcn_mfma_f32_16x16x32_bf16(afr[kk], bfr[ct][kk], pacc, 0, 0, 0);
      #pragma unroll
      for (int r = 0; r < 4; ++r)
        zred[p][wave][ct][lane][r] = pacc[r];
    }

    __syncthreads();   // the ONLY barrier per step

    // ---- owner: reduce 8 waves, gates (rcpf), publish v = t+1
    float z = xz;
    #pragma unroll
    for (int w = 0; w < 8; ++w) z += zred[p][w][ct_o][lred][rred];
    float u  = __expf(-z);
    float u2 = u * u;
    float sg = __builtin_amdgcn_rcpf(1.f + u);                 // sigmoid(z)
    float tz = (1.f - u2) * __builtin_amdgcn_rcpf(1.f + u2);   // tanh(z)
    cst  = sg * (cst + tz);
    float v  = __expf(-2.f * cst);
    float tc = (1.f - v) * __builtin_amdgcn_rcpf(1.f + v);     // tanh(c)
    hcur = sg * tc;

    PUBLISH(hcur, t + 1);                   // fire
    out[obase + (size_t)t * H_] = hcur;     // fp32 output (L2, overlaps drain)
    // PACING drain: granule-ack (~L3 RT) overlaps peers' publish window, so
    // the next spin's first attempt usually succeeds (the R10 lesson).
    asm volatile("s_waitcnt vmcnt(0)" ::: "memory");
    // next xz prefetch issued after drain: its L2 latency hides under the
    // next spin; it is consumed a full step later.
    xz = out[obase + (size_t)(t + 1 < S_ ? t + 1 : t) * H_];
  }
#undef PUBLISH

  // ---- hn, cn
  const size_t OFS = (size_t)B_ * S_ * H_;
  out[OFS + b * 1024 + col] = hcur;
  out[OFS + (size_t)B_ * H_ + b * 1024 + col] = cst;
}

// ============================================================================
extern "C" void kernel_launch(void* const* d_in, const int* in_sizes, int n_in,
                              void* d_out, int out_size, void* d_ws, size_t ws_size,
                              hipStream_t stream) {
  const float* x    = (const float*)d_in[0];
  const float* h0   = (const float*)d_in[1];
  const float* c0   = (const float*)d_in[2];
  const float* W    = (const float*)d_in[3];
  const float* bias = (const float*)d_in[4];
  float* out = (float*)d_out;

  u16* exch = (u16*)d_ws;   // 2 x 64 KB ping-pong, bf16 cells w/ LSB tags
  // 0xFF => every stale tag bit reads 1, mismatching the first expected tag
  // (0) in both parities; also kills cross-replay staleness.
  hipMemsetAsync(exch, 0xFF, 2 * EXN * sizeof(u16), stream);

  xz_gemm<<<dim3(8, 256), 256, 0, stream>>>(x, W, bias, out);
  lstm_rec<<<dim3(NWG), 512, 0, stream>>>(W, h0, c0, out, exch);
}